// Round 6
// baseline (91629.633 us; speedup 1.0000x reference)
//
#include <hip/hip_runtime.h>
#include <hip/hip_bf16.h>

#define TSTEPS 2048
#define NCHAIN 8
#define RDIM 1024
#define IDIM 128
#define HDIM 256
#define NB 32                    // blocks per chain
#define NBLOCKS (NB * NCHAIN)    // 256: 1 block/CU worst case -> co-resident

// Agent(device)-scope atomics: device-coherent, L1-bypassing, cross-XCD safe.
__device__ __forceinline__ float aload(const float* p) {
  return __hip_atomic_load(p, __ATOMIC_RELAXED, __HIP_MEMORY_SCOPE_AGENT);
}
__device__ __forceinline__ void astore(float* p, float v) {
  __hip_atomic_store(p, v, __ATOMIC_RELAXED, __HIP_MEMORY_SCOPE_AGENT);
}

__device__ __forceinline__ float wave_sum(float v) {
  v += __shfl_xor(v, 1);
  v += __shfl_xor(v, 2);
  v += __shfl_xor(v, 4);
  v += __shfl_xor(v, 8);
  v += __shfl_xor(v, 16);
  v += __shfl_xor(v, 32);
  return v;
}

// Monotonic per-chain barrier (32 arrivals per call). Watchdog bounds any
// pathological wait so failures surface as wrong values, not timeouts.
__device__ __forceinline__ void gbar(unsigned* cnt, unsigned target) {
  __threadfence();
  __syncthreads();
  if (threadIdx.x == 0) {
    __hip_atomic_fetch_add(cnt, 1u, __ATOMIC_ACQ_REL, __HIP_MEMORY_SCOPE_AGENT);
    unsigned it = 0;
    while (__hip_atomic_load(cnt, __ATOMIC_ACQUIRE, __HIP_MEMORY_SCOPE_AGENT) < target) {
      __builtin_amdgcn_s_sleep(1);
      if (++it > (1u << 15)) break;
    }
  }
  __syncthreads();
  __threadfence();
}

// Skewed software pipeline, ONE barrier per interval s (validated: R2/R3
// skewed and R4 unskewed produced bit-identical state trajectories):
//   phase A: x_s     = tanh(w_in u_s + W x_{s-1})   (s in [0, T))
//   phase B: p_{s-1} = x_{s-1} @ w_pca              (s in [1, T])
//   phase C: h_{s-2} = (1-z)h_{s-3} + z p_{s-2}     (s in [2, T+1])
// Parity-2 rings: every read hits the slot written in the previous interval,
// every write the other slot -> one barrier per interval is sufficient.
// Inputs fp32, math fp32, OUTPUT fp32 (reference output dtype is float32 --
// the R2-R4 failure was writing bf16 into the float* out buffer).
__global__ __launch_bounds__(256, 1) void esn_fused(
    const float* __restrict__ u, const float* __restrict__ w_in,
    const float* __restrict__ w, const float* __restrict__ w_bias,
    const float* __restrict__ w_pca, const float* __restrict__ wzp,
    const float* __restrict__ wzh, const float* __restrict__ bz,
    float* __restrict__ out,
    float* __restrict__ x_buf,   // [2][8][1024]
    float* __restrict__ p_buf,   // [2][8][256]
    float* __restrict__ h_buf,   // [2][8][256]
    unsigned* __restrict__ barr) // [8][64] padded counters
{
  const int bid = blockIdx.x;
  const int chain = bid & 7;
  const int sub = bid >> 3;            // 0..31
  const int tid = threadIdx.x;
  const int wave = tid >> 6;
  const int lane = tid & 63;
  unsigned* cnt = barr + chain * 64;

  // ---- phase-A weights: 8 rows of W per wave; lane owns cols [lane*16, +16) ----
  const int rrow0 = sub * 32 + wave * 8;
  float4 WA[8][4];
  #pragma unroll
  for (int j = 0; j < 8; ++j)
    #pragma unroll
    for (int i = 0; i < 4; ++i)
      WA[j][i] = *reinterpret_cast<const float4*>(
          w + (size_t)(rrow0 + j) * RDIM + lane * 16 + i * 4);
  float2 Wi[8];
  #pragma unroll
  for (int j = 0; j < 8; ++j)
    Wi[j] = *reinterpret_cast<const float2*>(w_in + (size_t)(rrow0 + j) * IDIM + lane * 2);
  const float wb = (lane < 8) ? w_bias[rrow0 + lane] : 0.f;

  // ---- phase-B weights: 2 cols of w_pca per wave; lane owns rows [lane*16, +16) ----
  const int pcol0 = sub * 8 + wave * 2;
  float Wp[2][16];
  #pragma unroll
  for (int j = 0; j < 2; ++j)
    #pragma unroll
    for (int k = 0; k < 16; ++k)
      Wp[j][k] = w_pca[(size_t)(lane * 16 + k) * HDIM + pcol0 + j];

  // ---- phase-C weights: 2 rows of wzp/wzh per wave; lane owns cols [lane*4, +4) ----
  const int grow0 = sub * 8 + wave * 2;
  float4 Zp[2], Zh[2];
  #pragma unroll
  for (int j = 0; j < 2; ++j) {
    Zp[j] = *reinterpret_cast<const float4*>(wzp + (size_t)(grow0 + j) * HDIM + lane * 4);
    Zh[j] = *reinterpret_cast<const float4*>(wzh + (size_t)(grow0 + j) * HDIM + lane * 4);
  }
  const float bzr = (lane < 2) ? bz[grow0 + lane] : 0.f;

  for (int s = 0; s < TSTEPS + 2; ++s) {
    // ---------------- phase A: x_s ----------------
    if (s < TSTEPS) {
      float acc[8];
      float2 uu = *reinterpret_cast<const float2*>(
          u + ((size_t)chain * TSTEPS + s) * IDIM + lane * 2);
      #pragma unroll
      for (int j = 0; j < 8; ++j) acc[j] = Wi[j].x * uu.x + Wi[j].y * uu.y;
      if (s > 0) {
        const float* xp = x_buf + ((((s - 1) & 1) * NCHAIN) + chain) * RDIM;
        float xc[16];
        #pragma unroll
        for (int k = 0; k < 16; ++k) xc[k] = aload(xp + lane * 16 + k);
        #pragma unroll
        for (int j = 0; j < 8; ++j) {
          float a = acc[j];
          #pragma unroll
          for (int i = 0; i < 4; ++i) {
            a += WA[j][i].x * xc[i * 4 + 0];
            a += WA[j][i].y * xc[i * 4 + 1];
            a += WA[j][i].z * xc[i * 4 + 2];
            a += WA[j][i].w * xc[i * 4 + 3];
          }
          acc[j] = a;
        }
      }
      #pragma unroll
      for (int j = 0; j < 8; ++j) acc[j] = wave_sum(acc[j]);
      float v = acc[0];
      #pragma unroll
      for (int j = 1; j < 8; ++j) v = (lane == j) ? acc[j] : v;
      if (lane < 8)
        astore(x_buf + (((s & 1) * NCHAIN) + chain) * RDIM + rrow0 + lane,
               tanhf(v + wb));
    }

    // ---------------- phase B: p_{s-1} ----------------
    if (s >= 1 && s <= TSTEPS) {
      const int t = s - 1;
      const float* xp = x_buf + (((t & 1) * NCHAIN) + chain) * RDIM;
      float xc[16];
      #pragma unroll
      for (int k = 0; k < 16; ++k) xc[k] = aload(xp + lane * 16 + k);
      float a0 = 0.f, a1 = 0.f;
      #pragma unroll
      for (int k = 0; k < 16; ++k) { a0 += Wp[0][k] * xc[k]; a1 += Wp[1][k] * xc[k]; }
      a0 = wave_sum(a0);
      a1 = wave_sum(a1);
      float v = (lane == 1) ? a1 : a0;
      if (lane < 2)
        astore(p_buf + (((t & 1) * NCHAIN) + chain) * HDIM + pcol0 + lane, v);
    }

    // ---------------- phase C: h_{s-2} ----------------
    if (s >= 2) {
      const int t = s - 2;
      const float* pv = p_buf + (((t & 1) * NCHAIN) + chain) * HDIM;
      const float* hv = h_buf + ((((t - 1) & 1) * NCHAIN) + chain) * HDIM;
      float pc[4], hc[4];
      #pragma unroll
      for (int e = 0; e < 4; ++e) pc[e] = aload(pv + lane * 4 + e);
      #pragma unroll
      for (int e = 0; e < 4; ++e) hc[e] = (t > 0) ? aload(hv + lane * 4 + e) : 0.f;
      float a0 = Zp[0].x * pc[0] + Zp[0].y * pc[1] + Zp[0].z * pc[2] + Zp[0].w * pc[3]
               + Zh[0].x * hc[0] + Zh[0].y * hc[1] + Zh[0].z * hc[2] + Zh[0].w * hc[3];
      float a1 = Zp[1].x * pc[0] + Zp[1].y * pc[1] + Zp[1].z * pc[2] + Zp[1].w * pc[3]
               + Zh[1].x * hc[0] + Zh[1].y * hc[1] + Zh[1].z * hc[2] + Zh[1].w * hc[3];
      a0 = wave_sum(a0);
      a1 = wave_sum(a1);
      float v = (lane == 1) ? a1 : a0;
      if (lane < 2) {
        const int row = grow0 + lane;
        float z = 1.f / (1.f + expf(-(v + bzr)));
        float pt = aload(pv + row);
        float hp = (t > 0) ? aload(hv + row) : 0.f;
        float hnew = hp + z * (pt - hp);
        astore(h_buf + (((t & 1) * NCHAIN) + chain) * HDIM + row, hnew);
        out[((size_t)chain * TSTEPS + t) * HDIM + row] = hnew;  // fp32 output
      }
    }

    if (s <= TSTEPS) gbar(cnt, (unsigned)(s + 1) * NB);
  }
}

extern "C" void kernel_launch(void* const* d_in, const int* in_sizes, int n_in,
                              void* d_out, int out_size, void* d_ws, size_t ws_size,
                              hipStream_t stream) {
  // Size-based remap (defensive); positional fallback. All fp32.
  const float* ptrs[8] = {nullptr};
  const int want[8] = {TSTEPS * NCHAIN * IDIM,  // u      2097152
                       RDIM * IDIM,             // w_in   131072
                       RDIM * RDIM,             // w      1048576
                       RDIM,                    // w_bias 1024
                       RDIM * HDIM,             // w_pca  262144
                       HDIM * HDIM,             // wzp    65536
                       HDIM * HDIM,             // wzh    65536
                       HDIM};                   // bz     256
  if (n_in == 8) {
    int used[8] = {0};
    for (int k = 0; k < 8; ++k) {
      for (int i = 0; i < n_in; ++i) {
        if (!used[i] && in_sizes[i] == want[k]) {
          ptrs[k] = (const float*)d_in[i];
          used[i] = 1;
          break;
        }
      }
    }
  }
  bool ok = true;
  for (int k = 0; k < 8; ++k) ok = ok && (ptrs[k] != nullptr);
  if (!ok)
    for (int k = 0; k < 8; ++k) ptrs[k] = (const float*)d_in[k];

  float* out = (float*)d_out;  // reference output dtype: float32

  // workspace layout (re-poisoned 0xAA before every launch -> must zero)
  float* x_buf = (float*)d_ws;                              // 2*8*1024
  float* p_buf = x_buf + 2 * NCHAIN * RDIM;                 // 2*8*256
  float* h_buf = p_buf + 2 * NCHAIN * HDIM;                 // 2*8*256
  unsigned* barr = (unsigned*)(h_buf + 2 * NCHAIN * HDIM);  // 8*64
  size_t zero_floats =
      (size_t)(2 * NCHAIN * RDIM + 2 * NCHAIN * HDIM * 2 + NCHAIN * 64);
  if (ws_size < zero_floats * 4) return;  // zero-output diagnostic signature
  hipMemsetAsync(d_ws, 0, zero_floats * 4, stream);

  esn_fused<<<dim3(NBLOCKS), dim3(256), 0, stream>>>(
      ptrs[0], ptrs[1], ptrs[2], ptrs[3], ptrs[4], ptrs[5], ptrs[6], ptrs[7],
      out, x_buf, p_buf, h_buf, barr);
}

// Round 7
// 15314.656 us; speedup vs baseline: 5.9831x; 5.9831x over previous
//
#include <hip/hip_runtime.h>
#include <hip/hip_bf16.h>

#define TSTEPS 2048
#define NCHAIN 8
#define RDIM 1024
#define IDIM 128
#define HDIM 256
#define NB 32                    // blocks per chain
#define NBLOCKS (NB * NCHAIN)    // 256: 1 block/CU worst case -> co-resident

// Agent(device)-scope RELAXED atomics: compile to sc-flagged accesses that
// bypass L1/L2 and are served at the device-coherent point (MALL). Because
// every cross-block datum moves through these, NO cache-maintenance fences
// (buffer_wbl2 / buffer_inv) are needed anywhere -- that was R6's 45us/step.
__device__ __forceinline__ float aload(const float* p) {
  return __hip_atomic_load(p, __ATOMIC_RELAXED, __HIP_MEMORY_SCOPE_AGENT);
}
__device__ __forceinline__ void astore(float* p, float v) {
  __hip_atomic_store(p, v, __ATOMIC_RELAXED, __HIP_MEMORY_SCOPE_AGENT);
}

__device__ __forceinline__ float wave_sum(float v) {
  v += __shfl_xor(v, 1);
  v += __shfl_xor(v, 2);
  v += __shfl_xor(v, 4);
  v += __shfl_xor(v, 8);
  v += __shfl_xor(v, 16);
  v += __shfl_xor(v, 32);
  return v;
}

// Monotonic per-chain barrier, fence-free protocol:
//  1) every wave drains its own MALL-bound stores (s_waitcnt vmcnt(0); the
//     "memory" clobber stops compiler reordering),
//  2) __syncthreads so ALL waves' stores are complete before arrival,
//  3) thread0: relaxed RMW arrival + relaxed spin (NO buffer_inv per poll),
//  4) __syncthreads releases the block; consumers' loads are sc-flagged so
//     they read MALL directly -- no acquire cache-op needed.
__device__ __forceinline__ void gbar(unsigned* cnt, unsigned target) {
  asm volatile("s_waitcnt vmcnt(0) lgkmcnt(0)" ::: "memory");
  __syncthreads();
  if (threadIdx.x == 0) {
    __hip_atomic_fetch_add(cnt, 1u, __ATOMIC_RELAXED, __HIP_MEMORY_SCOPE_AGENT);
    unsigned it = 0;
    while (__hip_atomic_load(cnt, __ATOMIC_RELAXED, __HIP_MEMORY_SCOPE_AGENT) < target) {
      __builtin_amdgcn_s_sleep(1);
      if (++it > (1u << 15)) break;   // watchdog: wrong > hung
    }
  }
  __syncthreads();
}

// Skewed software pipeline, ONE barrier per interval s (correctness proven in
// R6; R2-R4 cross-validation showed skewed == unskewed trajectories):
//   phase A: x_s     = tanh(w_in u_s + W x_{s-1})   (s in [0, T))
//   phase B: p_{s-1} = x_{s-1} @ w_pca              (s in [1, T])
//   phase C: h_{s-2} = (1-z)h_{s-3} + z p_{s-2}     (s in [2, T+1])
// Parity-2 rings: reads hit the slot written in the previous interval.
__global__ __launch_bounds__(256, 1) void esn_fused(
    const float* __restrict__ u, const float* __restrict__ w_in,
    const float* __restrict__ w, const float* __restrict__ w_bias,
    const float* __restrict__ w_pca, const float* __restrict__ wzp,
    const float* __restrict__ wzh, const float* __restrict__ bz,
    float* __restrict__ out,
    float* __restrict__ x_buf,   // [2][8][1024]
    float* __restrict__ p_buf,   // [2][8][256]
    float* __restrict__ h_buf,   // [2][8][256]
    unsigned* __restrict__ barr) // [8][64] padded counters
{
  const int bid = blockIdx.x;
  const int chain = bid & 7;
  const int sub = bid >> 3;            // 0..31
  const int tid = threadIdx.x;
  const int wave = tid >> 6;
  const int lane = tid & 63;
  unsigned* cnt = barr + chain * 64;

  // ---- phase-A weights: 8 rows of W per wave; lane owns cols [lane*16, +16) ----
  const int rrow0 = sub * 32 + wave * 8;
  float4 WA[8][4];
  #pragma unroll
  for (int j = 0; j < 8; ++j)
    #pragma unroll
    for (int i = 0; i < 4; ++i)
      WA[j][i] = *reinterpret_cast<const float4*>(
          w + (size_t)(rrow0 + j) * RDIM + lane * 16 + i * 4);
  float2 Wi[8];
  #pragma unroll
  for (int j = 0; j < 8; ++j)
    Wi[j] = *reinterpret_cast<const float2*>(w_in + (size_t)(rrow0 + j) * IDIM + lane * 2);
  const float wb = (lane < 8) ? w_bias[rrow0 + lane] : 0.f;

  // ---- phase-B weights: 2 cols of w_pca per wave; lane owns rows [lane*16, +16) ----
  const int pcol0 = sub * 8 + wave * 2;
  float Wp[2][16];
  #pragma unroll
  for (int j = 0; j < 2; ++j)
    #pragma unroll
    for (int k = 0; k < 16; ++k)
      Wp[j][k] = w_pca[(size_t)(lane * 16 + k) * HDIM + pcol0 + j];

  // ---- phase-C weights: 2 rows of wzp/wzh per wave; lane owns cols [lane*4, +4) ----
  const int grow0 = sub * 8 + wave * 2;
  float4 Zp[2], Zh[2];
  #pragma unroll
  for (int j = 0; j < 2; ++j) {
    Zp[j] = *reinterpret_cast<const float4*>(wzp + (size_t)(grow0 + j) * HDIM + lane * 4);
    Zh[j] = *reinterpret_cast<const float4*>(wzh + (size_t)(grow0 + j) * HDIM + lane * 4);
  }
  const float bzr = (lane < 2) ? bz[grow0 + lane] : 0.f;

  for (int s = 0; s < TSTEPS + 2; ++s) {
    // ---------------- phase A: x_s ----------------
    if (s < TSTEPS) {
      float acc[8];
      float2 uu = *reinterpret_cast<const float2*>(
          u + ((size_t)chain * TSTEPS + s) * IDIM + lane * 2);
      #pragma unroll
      for (int j = 0; j < 8; ++j) acc[j] = Wi[j].x * uu.x + Wi[j].y * uu.y;
      if (s > 0) {
        const float* xp = x_buf + ((((s - 1) & 1) * NCHAIN) + chain) * RDIM;
        float xc[16];
        #pragma unroll
        for (int k = 0; k < 16; ++k) xc[k] = aload(xp + lane * 16 + k);
        #pragma unroll
        for (int j = 0; j < 8; ++j) {
          float a = acc[j];
          #pragma unroll
          for (int i = 0; i < 4; ++i) {
            a += WA[j][i].x * xc[i * 4 + 0];
            a += WA[j][i].y * xc[i * 4 + 1];
            a += WA[j][i].z * xc[i * 4 + 2];
            a += WA[j][i].w * xc[i * 4 + 3];
          }
          acc[j] = a;
        }
      }
      #pragma unroll
      for (int j = 0; j < 8; ++j) acc[j] = wave_sum(acc[j]);
      float v = acc[0];
      #pragma unroll
      for (int j = 1; j < 8; ++j) v = (lane == j) ? acc[j] : v;
      if (lane < 8)
        astore(x_buf + (((s & 1) * NCHAIN) + chain) * RDIM + rrow0 + lane,
               tanhf(v + wb));
    }

    // ---------------- phase B: p_{s-1} ----------------
    if (s >= 1 && s <= TSTEPS) {
      const int t = s - 1;
      const float* xp = x_buf + (((t & 1) * NCHAIN) + chain) * RDIM;
      float xc[16];
      #pragma unroll
      for (int k = 0; k < 16; ++k) xc[k] = aload(xp + lane * 16 + k);
      float a0 = 0.f, a1 = 0.f;
      #pragma unroll
      for (int k = 0; k < 16; ++k) { a0 += Wp[0][k] * xc[k]; a1 += Wp[1][k] * xc[k]; }
      a0 = wave_sum(a0);
      a1 = wave_sum(a1);
      float v = (lane == 1) ? a1 : a0;
      if (lane < 2)
        astore(p_buf + (((t & 1) * NCHAIN) + chain) * HDIM + pcol0 + lane, v);
    }

    // ---------------- phase C: h_{s-2} ----------------
    if (s >= 2) {
      const int t = s - 2;
      const float* pv = p_buf + (((t & 1) * NCHAIN) + chain) * HDIM;
      const float* hv = h_buf + ((((t - 1) & 1) * NCHAIN) + chain) * HDIM;
      float pc[4], hc[4];
      #pragma unroll
      for (int e = 0; e < 4; ++e) pc[e] = aload(pv + lane * 4 + e);
      #pragma unroll
      for (int e = 0; e < 4; ++e) hc[e] = (t > 0) ? aload(hv + lane * 4 + e) : 0.f;
      float a0 = Zp[0].x * pc[0] + Zp[0].y * pc[1] + Zp[0].z * pc[2] + Zp[0].w * pc[3]
               + Zh[0].x * hc[0] + Zh[0].y * hc[1] + Zh[0].z * hc[2] + Zh[0].w * hc[3];
      float a1 = Zp[1].x * pc[0] + Zp[1].y * pc[1] + Zp[1].z * pc[2] + Zp[1].w * pc[3]
               + Zh[1].x * hc[0] + Zh[1].y * hc[1] + Zh[1].z * hc[2] + Zh[1].w * hc[3];
      a0 = wave_sum(a0);
      a1 = wave_sum(a1);
      float v = (lane == 1) ? a1 : a0;
      if (lane < 2) {
        const int row = grow0 + lane;
        float z = 1.f / (1.f + expf(-(v + bzr)));
        float pt = aload(pv + row);
        float hp = (t > 0) ? aload(hv + row) : 0.f;
        float hnew = hp + z * (pt - hp);
        astore(h_buf + (((t & 1) * NCHAIN) + chain) * HDIM + row, hnew);
        out[((size_t)chain * TSTEPS + t) * HDIM + row] = hnew;  // fp32 output
      }
    }

    if (s <= TSTEPS) gbar(cnt, (unsigned)(s + 1) * NB);
  }
}

extern "C" void kernel_launch(void* const* d_in, const int* in_sizes, int n_in,
                              void* d_out, int out_size, void* d_ws, size_t ws_size,
                              hipStream_t stream) {
  // Size-based remap (defensive); positional fallback. All fp32.
  const float* ptrs[8] = {nullptr};
  const int want[8] = {TSTEPS * NCHAIN * IDIM,  // u      2097152
                       RDIM * IDIM,             // w_in   131072
                       RDIM * RDIM,             // w      1048576
                       RDIM,                    // w_bias 1024
                       RDIM * HDIM,             // w_pca  262144
                       HDIM * HDIM,             // wzp    65536
                       HDIM * HDIM,             // wzh    65536
                       HDIM};                   // bz     256
  if (n_in == 8) {
    int used[8] = {0};
    for (int k = 0; k < 8; ++k) {
      for (int i = 0; i < n_in; ++i) {
        if (!used[i] && in_sizes[i] == want[k]) {
          ptrs[k] = (const float*)d_in[i];
          used[i] = 1;
          break;
        }
      }
    }
  }
  bool ok = true;
  for (int k = 0; k < 8; ++k) ok = ok && (ptrs[k] != nullptr);
  if (!ok)
    for (int k = 0; k < 8; ++k) ptrs[k] = (const float*)d_in[k];

  float* out = (float*)d_out;  // reference output dtype: float32

  // workspace layout (re-poisoned 0xAA before every launch -> must zero)
  float* x_buf = (float*)d_ws;                              // 2*8*1024
  float* p_buf = x_buf + 2 * NCHAIN * RDIM;                 // 2*8*256
  float* h_buf = p_buf + 2 * NCHAIN * HDIM;                 // 2*8*256
  unsigned* barr = (unsigned*)(h_buf + 2 * NCHAIN * HDIM);  // 8*64
  size_t zero_floats =
      (size_t)(2 * NCHAIN * RDIM + 2 * NCHAIN * HDIM * 2 + NCHAIN * 64);
  if (ws_size < zero_floats * 4) return;  // zero-output diagnostic signature
  hipMemsetAsync(d_ws, 0, zero_floats * 4, stream);

  esn_fused<<<dim3(NBLOCKS), dim3(256), 0, stream>>>(
      ptrs[0], ptrs[1], ptrs[2], ptrs[3], ptrs[4], ptrs[5], ptrs[6], ptrs[7],
      out, x_buf, p_buf, h_buf, barr);
}

// Round 8
// 13709.973 us; speedup vs baseline: 6.6834x; 1.1170x over previous
//
#include <hip/hip_runtime.h>
#include <hip/hip_bf16.h>

#define TSTEPS 2048
#define NCHAIN 8
#define RDIM 1024
#define IDIM 128
#define HDIM 256
#define NB 16                    // blocks per chain (was 32)
#define NTHR 512                 // threads per block (8 waves)
#define NBLOCKS (NB * NCHAIN)    // 128 blocks: always co-resident

typedef unsigned long long u64_t;

// Agent(device)-scope RELAXED atomics: sc-flagged, L1/L2-bypassing, served at
// the device-coherent point. No cache-maintenance fences anywhere (R6 lesson).
__device__ __forceinline__ float aload(const float* p) {
  return __hip_atomic_load(p, __ATOMIC_RELAXED, __HIP_MEMORY_SCOPE_AGENT);
}
__device__ __forceinline__ void astore(float* p, float v) {
  __hip_atomic_store(p, v, __ATOMIC_RELAXED, __HIP_MEMORY_SCOPE_AGENT);
}
// 8-byte sc load: halves request count vs per-float loads.
__device__ __forceinline__ float2 aload2(const float* p) {
  u64_t q = __hip_atomic_load(reinterpret_cast<const u64_t*>(p),
                              __ATOMIC_RELAXED, __HIP_MEMORY_SCOPE_AGENT);
  union { u64_t u; float2 f; } c; c.u = q;
  return c.f;
}

__device__ __forceinline__ float wave_sum(float v) {
  v += __shfl_xor(v, 1);
  v += __shfl_xor(v, 2);
  v += __shfl_xor(v, 4);
  v += __shfl_xor(v, 8);
  v += __shfl_xor(v, 16);
  v += __shfl_xor(v, 32);
  return v;
}

// Monotonic per-chain barrier (16 arrivals/call), fence-free: per-wave vmcnt
// drain + __syncthreads before a fire-and-forget relaxed RMW; relaxed spin.
__device__ __forceinline__ void gbar(unsigned* cnt, unsigned target) {
  asm volatile("s_waitcnt vmcnt(0) lgkmcnt(0)" ::: "memory");
  __syncthreads();
  if (threadIdx.x == 0) {
    __hip_atomic_fetch_add(cnt, 1u, __ATOMIC_RELAXED, __HIP_MEMORY_SCOPE_AGENT);
    unsigned it = 0;
    while (__hip_atomic_load(cnt, __ATOMIC_RELAXED, __HIP_MEMORY_SCOPE_AGENT) < target) {
      __builtin_amdgcn_s_sleep(1);
      if (++it > (1u << 15)) break;   // watchdog: wrong > hung
    }
  }
  __syncthreads();
}

// Skewed pipeline, ONE barrier per interval s (validated R6/R7):
//   phase A: x_s     = tanh(w_in u_s + W x_{s-1})   (s in [0, T))
//   phase B: p_{s-1} = x_{s-1} @ w_pca              (s in [1, T])
//   phase C: h_{s-2} = (1-z)h_{s-3} + z p_{s-2}     (s in [2, T+1])
// A and B read the SAME x_{s-1} ring slot -> loaded once per interval.
__global__ __launch_bounds__(NTHR, 2) void esn_fused(
    const float* __restrict__ u, const float* __restrict__ w_in,
    const float* __restrict__ w, const float* __restrict__ w_bias,
    const float* __restrict__ w_pca, const float* __restrict__ wzp,
    const float* __restrict__ wzh, const float* __restrict__ bz,
    float* __restrict__ out,
    float* __restrict__ x_buf,   // [2][8][1024]
    float* __restrict__ p_buf,   // [2][8][256]
    float* __restrict__ h_buf,   // [2][8][256]
    unsigned* __restrict__ barr) // [8][64] padded counters
{
  const int bid = blockIdx.x;
  const int chain = bid & 7;
  const int sub = bid >> 3;            // 0..15
  const int tid = threadIdx.x;
  const int wave = tid >> 6;           // 0..7
  const int lane = tid & 63;
  unsigned* cnt = barr + chain * 64;

  // ---- phase-A weights: 8 rows of W per wave; lane owns cols [lane*16, +16) ----
  const int rrow0 = sub * 64 + wave * 8;
  float4 WA[8][4];
  #pragma unroll
  for (int j = 0; j < 8; ++j)
    #pragma unroll
    for (int i = 0; i < 4; ++i)
      WA[j][i] = *reinterpret_cast<const float4*>(
          w + (size_t)(rrow0 + j) * RDIM + lane * 16 + i * 4);
  float2 Wi[8];
  #pragma unroll
  for (int j = 0; j < 8; ++j)
    Wi[j] = *reinterpret_cast<const float2*>(w_in + (size_t)(rrow0 + j) * IDIM + lane * 2);
  const float wb = (lane < 8) ? w_bias[rrow0 + lane] : 0.f;

  // ---- phase-B weights: 2 cols of w_pca per wave; lane owns rows [lane*16, +16) ----
  const int pcol0 = sub * 16 + wave * 2;
  float Wp[2][16];
  #pragma unroll
  for (int j = 0; j < 2; ++j)
    #pragma unroll
    for (int k = 0; k < 16; ++k)
      Wp[j][k] = w_pca[(size_t)(lane * 16 + k) * HDIM + pcol0 + j];

  // ---- phase-C weights: 2 rows of wzp/wzh per wave; lane owns cols [lane*4, +4) ----
  const int grow0 = sub * 16 + wave * 2;
  float4 Zp[2], Zh[2];
  #pragma unroll
  for (int j = 0; j < 2; ++j) {
    Zp[j] = *reinterpret_cast<const float4*>(wzp + (size_t)(grow0 + j) * HDIM + lane * 4);
    Zh[j] = *reinterpret_cast<const float4*>(wzh + (size_t)(grow0 + j) * HDIM + lane * 4);
  }
  const float bzr = (lane < 2) ? bz[grow0 + lane] : 0.f;

  for (int s = 0; s < TSTEPS + 2; ++s) {
    // ---- shared load: x_{s-1}, used by BOTH phase A and phase B ----
    float xc[16];
    const bool xc_valid = (s >= 1 && s <= TSTEPS);
    if (xc_valid) {
      const float* xp = x_buf + ((((s - 1) & 1) * NCHAIN) + chain) * RDIM + lane * 16;
      #pragma unroll
      for (int k = 0; k < 8; ++k) {
        float2 f = aload2(xp + 2 * k);
        xc[2 * k] = f.x;
        xc[2 * k + 1] = f.y;
      }
    }

    // ---------------- phase A: x_s ----------------
    if (s < TSTEPS) {
      float acc[8];
      float2 uu = *reinterpret_cast<const float2*>(
          u + ((size_t)chain * TSTEPS + s) * IDIM + lane * 2);
      #pragma unroll
      for (int j = 0; j < 8; ++j) acc[j] = Wi[j].x * uu.x + Wi[j].y * uu.y;
      if (s > 0) {
        #pragma unroll
        for (int j = 0; j < 8; ++j) {
          float a = acc[j];
          #pragma unroll
          for (int i = 0; i < 4; ++i) {
            a += WA[j][i].x * xc[i * 4 + 0];
            a += WA[j][i].y * xc[i * 4 + 1];
            a += WA[j][i].z * xc[i * 4 + 2];
            a += WA[j][i].w * xc[i * 4 + 3];
          }
          acc[j] = a;
        }
      }
      #pragma unroll
      for (int j = 0; j < 8; ++j) acc[j] = wave_sum(acc[j]);
      float v = acc[0];
      #pragma unroll
      for (int j = 1; j < 8; ++j) v = (lane == j) ? acc[j] : v;
      if (lane < 8)
        astore(x_buf + (((s & 1) * NCHAIN) + chain) * RDIM + rrow0 + lane,
               tanhf(v + wb));
    }

    // ---------------- phase B: p_{s-1} (reuses xc) ----------------
    if (xc_valid) {
      const int t = s - 1;
      float a0 = 0.f, a1 = 0.f;
      #pragma unroll
      for (int k = 0; k < 16; ++k) { a0 += Wp[0][k] * xc[k]; a1 += Wp[1][k] * xc[k]; }
      a0 = wave_sum(a0);
      a1 = wave_sum(a1);
      float v = (lane == 1) ? a1 : a0;
      if (lane < 2)
        astore(p_buf + (((t & 1) * NCHAIN) + chain) * HDIM + pcol0 + lane, v);
    }

    // ---------------- phase C: h_{s-2} ----------------
    if (s >= 2) {
      const int t = s - 2;
      const float* pv = p_buf + (((t & 1) * NCHAIN) + chain) * HDIM;
      const float* hv = h_buf + ((((t - 1) & 1) * NCHAIN) + chain) * HDIM;
      float pc[4], hc[4];
      {
        float2 f0 = aload2(pv + lane * 4), f1 = aload2(pv + lane * 4 + 2);
        pc[0] = f0.x; pc[1] = f0.y; pc[2] = f1.x; pc[3] = f1.y;
      }
      if (t > 0) {
        float2 f0 = aload2(hv + lane * 4), f1 = aload2(hv + lane * 4 + 2);
        hc[0] = f0.x; hc[1] = f0.y; hc[2] = f1.x; hc[3] = f1.y;
      } else {
        hc[0] = hc[1] = hc[2] = hc[3] = 0.f;
      }
      float a0 = Zp[0].x * pc[0] + Zp[0].y * pc[1] + Zp[0].z * pc[2] + Zp[0].w * pc[3]
               + Zh[0].x * hc[0] + Zh[0].y * hc[1] + Zh[0].z * hc[2] + Zh[0].w * hc[3];
      float a1 = Zp[1].x * pc[0] + Zp[1].y * pc[1] + Zp[1].z * pc[2] + Zp[1].w * pc[3]
               + Zh[1].x * hc[0] + Zh[1].y * hc[1] + Zh[1].z * hc[2] + Zh[1].w * hc[3];
      a0 = wave_sum(a0);
      a1 = wave_sum(a1);
      float v = (lane == 1) ? a1 : a0;
      if (lane < 2) {
        const int row = grow0 + lane;
        float z = 1.f / (1.f + expf(-(v + bzr)));
        float pt = aload(pv + row);
        float hp = (t > 0) ? aload(hv + row) : 0.f;
        float hnew = hp + z * (pt - hp);
        astore(h_buf + (((t & 1) * NCHAIN) + chain) * HDIM + row, hnew);
        out[((size_t)chain * TSTEPS + t) * HDIM + row] = hnew;  // fp32 output
      }
    }

    if (s <= TSTEPS) gbar(cnt, (unsigned)(s + 1) * NB);
  }
}

extern "C" void kernel_launch(void* const* d_in, const int* in_sizes, int n_in,
                              void* d_out, int out_size, void* d_ws, size_t ws_size,
                              hipStream_t stream) {
  // Size-based remap (defensive); positional fallback. All fp32.
  const float* ptrs[8] = {nullptr};
  const int want[8] = {TSTEPS * NCHAIN * IDIM,  // u      2097152
                       RDIM * IDIM,             // w_in   131072
                       RDIM * RDIM,             // w      1048576
                       RDIM,                    // w_bias 1024
                       RDIM * HDIM,             // w_pca  262144
                       HDIM * HDIM,             // wzp    65536
                       HDIM * HDIM,             // wzh    65536
                       HDIM};                   // bz     256
  if (n_in == 8) {
    int used[8] = {0};
    for (int k = 0; k < 8; ++k) {
      for (int i = 0; i < n_in; ++i) {
        if (!used[i] && in_sizes[i] == want[k]) {
          ptrs[k] = (const float*)d_in[i];
          used[i] = 1;
          break;
        }
      }
    }
  }
  bool ok = true;
  for (int k = 0; k < 8; ++k) ok = ok && (ptrs[k] != nullptr);
  if (!ok)
    for (int k = 0; k < 8; ++k) ptrs[k] = (const float*)d_in[k];

  float* out = (float*)d_out;  // reference output dtype: float32

  // workspace layout (re-poisoned 0xAA before every launch -> must zero)
  float* x_buf = (float*)d_ws;                              // 2*8*1024
  float* p_buf = x_buf + 2 * NCHAIN * RDIM;                 // 2*8*256
  float* h_buf = p_buf + 2 * NCHAIN * HDIM;                 // 2*8*256
  unsigned* barr = (unsigned*)(h_buf + 2 * NCHAIN * HDIM);  // 8*64
  size_t zero_floats =
      (size_t)(2 * NCHAIN * RDIM + 2 * NCHAIN * HDIM * 2 + NCHAIN * 64);
  if (ws_size < zero_floats * 4) return;  // zero-output diagnostic signature
  hipMemsetAsync(d_ws, 0, zero_floats * 4, stream);

  esn_fused<<<dim3(NBLOCKS), dim3(NTHR), 0, stream>>>(
      ptrs[0], ptrs[1], ptrs[2], ptrs[3], ptrs[4], ptrs[5], ptrs[6], ptrs[7],
      out, x_buf, p_buf, h_buf, barr);
}